// Round 2
// baseline (202.514 us; speedup 1.0000x reference)
//
#include <hip/hip_runtime.h>

// Problem constants (fixed by the reference)
#define N_NODES 20000
#define N_EDGES 320000
#define ETOT    (N_EDGES + N_NODES)   // edges + self-loops = 340000
#define HEADS   10
#define F_IN    32
#define C1      (HEADS * F_IN)        // 320
#define C2      128
#define NB      100
#define PER     200
#define CAP     96                    // CSR bucket capacity (max in-degree << 96)
#define HSTRIDE 328                   // padded tile row stride (ushort); 328*2=656 is 16B-aligned
#define X2STRIDE 136                  // padded x2-tile row stride (f16)
#define SPLIT   10000                 // source-partition split: 2.56MB halves fit per-XCD L2

typedef __attribute__((ext_vector_type(8))) short bf16x8;   // MFMA A/B frag (4 VGPRs)
typedef __attribute__((ext_vector_type(4))) float floatx4;  // MFMA C/D frag
typedef _Float16 f16;
typedef _Float16 f16x2 __attribute__((ext_vector_type(2)));
typedef _Float16 f16x8 __attribute__((ext_vector_type(8)));

static __device__ __forceinline__ unsigned short f2bf(float f) {
    unsigned int u = __float_as_uint(f);
    unsigned int r = (u + 0x7fffu + ((u >> 16) & 1u)) >> 16;   // RNE
    return (unsigned short)r;
}

// ---------------------------------------------------------------------------
// Mega prep: CSR scatter + layer-1 scores (local WA fold) + W2/W1/FC B-frag
// prep + feats->f16.  cursor/pooled/done zeroed by a prior hipMemsetAsync.
// All branches are independent work — no tail serialization.
// ---------------------------------------------------------------------------
#define SCAT_BLOCKS  ((ETOT + 255) / 256)               // 1329
#define SCORE_BLOCKS ((N_NODES + 63) / 64)              // 313
#define W2P_BLOCKS   ((C1 * C2 + 255) / 256)            // 160
#define W1P_BLOCKS   ((HEADS * F_IN * F_IN + 255) / 256)// 40
#define FCP_BLOCKS   ((C2 * C2 + 255) / 256)            // 64
#define F16_BLOCKS   ((N_NODES * F_IN / 4 + 255) / 256) // 625
__global__ __launch_bounds__(256) void mega_prep_kernel(
        const int* __restrict__ ei, int* __restrict__ cursor, int* __restrict__ csr_src,
        const float* __restrict__ feats, f16* __restrict__ feats16,
        const float* __restrict__ W1, unsigned short* __restrict__ W1p,
        const float* __restrict__ W2, unsigned short* __restrict__ W2p,
        const float* __restrict__ fcw, f16* __restrict__ FCp,
        const float* __restrict__ a1s, const float* __restrict__ a1d,
        float* __restrict__ s_src, float* __restrict__ s_dst) {
    unsigned int b = blockIdx.x;
    if (b < SCAT_BLOCKS) {
        int e = b * 256 + threadIdx.x;
        if (e >= ETOT) return;
        int s, d;
        if (e < N_EDGES) { s = ei[e]; d = ei[N_EDGES + e]; }
        else             { s = e - N_EDGES; d = s; }
        int pos = atomicAdd(&cursor[d], 1);
        csr_src[(size_t)d * CAP + pos] = s;
        return;
    }
    b -= SCAT_BLOCKS;
    if (b < SCORE_BLOCKS) {
        __shared__ __align__(16) float A[64 * F_IN];   // 8 KB
        __shared__ float Ws[C1], Wd[C1];
        int t = threadIdx.x;
        // fold attention vectors through W1 locally
        for (int o = t; o < C1; o += 256) {
            int k = o & 31, h = o >> 5;
            float ss = 0.f, dd = 0.f;
#pragma unroll
            for (int f = 0; f < F_IN; f++) {
                float wv = W1[k * C1 + h * 32 + f];
                ss += wv * a1s[h * 32 + f];
                dd += wv * a1d[h * 32 + f];
            }
            Ws[k * HEADS + h] = ss;
            Wd[k * HEADS + h] = dd;
        }
        int n0 = b * 64;
        int nrows = min(64, N_NODES - n0);
        const float4* fs = (const float4*)(feats + (size_t)n0 * F_IN);
        float4* Af = (float4*)A;
        for (int i = t; i < nrows * 8; i += 256) Af[i] = fs[i];
        __syncthreads();
        for (int o = t; o < nrows * HEADS; o += 256) {
            int nl = o / HEADS, h = o - nl * HEADS;
            const float* ar = A + nl * F_IN;
            float ss = 0.f, dd = 0.f;
#pragma unroll
            for (int k = 0; k < F_IN; k++) {
                float av = ar[k];
                ss += av * Ws[k * HEADS + h];
                dd += av * Wd[k * HEADS + h];
            }
            s_src[(size_t)(n0 + nl) * HEADS + h] = ss;
            s_dst[(size_t)(n0 + nl) * HEADS + h] = dd;
        }
        return;
    }
    b -= SCORE_BLOCKS;
    if (b < W2P_BLOCKS) {
        int o = b * 256 + threadIdx.x;   // 40960
        if (o >= C1 * C2) return;
        int j    = o & 7;
        int lane = (o >> 3) & 63;
        int ct   = (o >> 9) & 7;
        int kb   = o >> 12;
        int k = kb * 32 + (lane >> 4) * 8 + j;
        int n = ct * 16 + (lane & 15);
        W2p[o] = f2bf(W2[k * C2 + n]);
        return;
    }
    b -= W2P_BLOCKS;
    if (b < W1P_BLOCKS) {
        int o = b * 256 + threadIdx.x;   // 10240
        if (o >= HEADS * F_IN * F_IN) return;
        int j    = o & 7;
        int lane = (o >> 3) & 63;
        int ct   = (o >> 9) & 1;
        int h    = o >> 10;
        int k = (lane >> 4) * 8 + j;
        int f = ct * 16 + (lane & 15);
        W1p[o] = f2bf(W1[k * C1 + h * 32 + f]);
        return;
    }
    b -= W1P_BLOCKS;
    if (b < FCP_BLOCKS) {
        int o = b * 256 + threadIdx.x;   // 16384
        if (o >= C2 * C2) return;
        int j    = o & 7;
        int lane = (o >> 3) & 63;
        int ct   = (o >> 9) & 7;
        int kb   = o >> 12;
        int k = kb * 32 + (lane >> 4) * 8 + j;
        int n = ct * 16 + (lane & 15);
        FCp[o] = (f16)fcw[k * C2 + n];
        return;
    }
    b -= FCP_BLOCKS;
    {
        int o = b * 256 + threadIdx.x;
        if (o < N_NODES * F_IN / 4) {
            float4 v = ((const float4*)feats)[o];
            f16* d = feats16 + 4 * o;
            d[0] = (f16)v.x; d[1] = (f16)v.y; d[2] = (f16)v.z; d[3] = (f16)v.w;
        }
    }
}

// ---------------------------------------------------------------------------
// FUSED layer-1 aggregation + h1 transform + gemm2.
// Phase 1 restructured (round 2): 2 CONCURRENT nodes per wave, 32 lanes each.
//   - avg degree = 17, so a 64-wide score chunk was 27% utilized; 32-wide is
//     ~53% and two node-chains run in parallel instead of 4 in series.
//   - each half owns its node's k-columns end-to-end: no cross-half shfl.
// Phase 2a: h1 = elu(G @ W1 + b1) per head (heads strided over waves) -> H.
// Phase 2b: gemm2 xw2 = H @ W2 (2 col-tiles per wave) + a2 scores.
// ---------------------------------------------------------------------------
__global__ __launch_bounds__(256) void agg1h1g2_kernel(
        const f16* __restrict__ feats16, const float* __restrict__ s_src,
        const float* __restrict__ s_dst, const int* __restrict__ deg_arr,
        const int* __restrict__ csr_src,
        const unsigned short* __restrict__ W1p, const float* __restrict__ b1,
        const unsigned short* __restrict__ W2p,
        const float* __restrict__ a_src, const float* __restrict__ a_dst,
        f16* __restrict__ xw2h, float* __restrict__ s_src2, float* __restrict__ s_dst2) {
    union Smem {
        struct { f16 P[4][2][HEADS * 32]; int S[4][2][32]; } p1;  // 6.1 KB
        unsigned short H[16 * HSTRIDE];                           // 10.25 KB
    };
    __shared__ __align__(16) Smem u;
    __shared__ __align__(16) unsigned short G[16 * HSTRIDE];  // gn tile, bf16
    __shared__ float redS[4][16], redD[4][16];

    int wslot = threadIdx.x >> 6;
    int lane  = threadIdx.x & 63;
    int l = lane & 31, half = lane >> 5;   // l doubles as k-index and edge-slot
    int row0 = blockIdx.x * 16;            // 1250 blocks x 16 nodes
    f16* P = u.p1.P[wslot][half];
    int* S = u.p1.S[wslot][half];
    const f16x2 ones = {(f16)1.f, (f16)1.f};
    const char* fb = (const char*)feats16 + 2 * l;   // lane's k-column base

    // ---- phase 1: 2 reps x 2 concurrent nodes per wave ----
    for (int rep = 0; rep < 2; rep++) {
        int r = wslot * 4 + rep * 2 + half;
        int n = row0 + r;
        int beg = n * CAP, deg = deg_arr[n];
        const float* sdp = s_dst + (size_t)n * HEADS;
        float sd[10];
#pragma unroll
        for (int q = 0; q < 5; q++) {
            float2 v = *(const float2*)(sdp + 2 * q);
            sd[2 * q] = v.x; sd[2 * q + 1] = v.y;
        }
        float g[10], la[10];
#pragma unroll
        for (int h = 0; h < 10; h++) { g[h] = 0.f; la[h] = 0.f; }

        for (int c0 = 0; c0 < deg; c0 += 32) {     // trip count diverges per half: OK
            int dc = min(deg - c0, 32);
            bool act = l < dc;
            int s_e = csr_src[beg + c0 + min(l, dc - 1)];
            const float* ssp = s_src + (size_t)s_e * HEADS;
            float p[10];
#pragma unroll
            for (int q = 0; q < 5; q++) {
                float2 v = *(const float2*)(ssp + 2 * q);
                float e0 = v.x + sd[2 * q];
                float e1 = v.y + sd[2 * q + 1];
                e0 = (e0 >= 0.f) ? e0 : 0.2f * e0;   // leaky_relu(0.2)
                e1 = (e1 >= 0.f) ? e1 : 0.2f * e1;
                p[2 * q]     = act ? __expf(e0) : 0.f;
                p[2 * q + 1] = act ? __expf(e1) : 0.f;
            }
            S[l] = s_e << 6;   // BYTE offset: row = 32 f16 = 64 B
#pragma unroll
            for (int h = 0; h < 10; h++) P[h * 32 + l] = (f16)p[h];
            asm volatile("s_waitcnt lgkmcnt(0)" ::: "memory");

            int dcp = (dc + 1) & ~1;
            for (int i = 0; i < dcp; i += 2) {
                int2 ss2 = *(const int2*)&S[i];
                f16x2 v;
                v.x = *(const f16*)(fb + ss2.x);
                v.y = *(const f16*)(fb + ss2.y);
#pragma unroll
                for (int h = 0; h < 10; h++) {
                    f16x2 pp = *(const f16x2*)&P[h * 32 + i];
                    g[h]  = __builtin_amdgcn_fdot2(pp, v, g[h], false);
                    la[h] = __builtin_amdgcn_fdot2(pp, ones, la[h], false);
                }
            }
            asm volatile("s_waitcnt lgkmcnt(0)" ::: "memory");
        }
        unsigned short* gr = &G[r * HSTRIDE + l];
#pragma unroll
        for (int h = 0; h < 10; h++)
            gr[h * 32] = f2bf(g[h] / fmaxf(la[h], 1e-16f));
    }
    __syncthreads();   // G complete; P/S dead -> union region becomes H

    // ---- phase 2a: h1 = elu(G @ W1 + b1), heads strided over waves ----
    int quad = lane >> 4, col = lane & 15;
    for (int h = wslot; h < 10; h += 4) {
        bf16x8 a = *(const bf16x8*)&G[col * HSTRIDE + h * 32 + quad * 8];
        bf16x8 bA = ((const bf16x8*)W1p)[(h * 2 + 0) * 64 + lane];
        bf16x8 bB = ((const bf16x8*)W1p)[(h * 2 + 1) * 64 + lane];
        floatx4 z = {0.f, 0.f, 0.f, 0.f};
        floatx4 c0 = __builtin_amdgcn_mfma_f32_16x16x32_bf16(a, bA, z, 0, 0, 0);
        floatx4 c1 = __builtin_amdgcn_mfma_f32_16x16x32_bf16(a, bB, z, 0, 0, 0);
        float bias0 = b1[h * 32 + col];
        float bias1 = b1[h * 32 + 16 + col];
#pragma unroll
        for (int reg = 0; reg < 4; reg++) {
            int rr = quad * 4 + reg;
            float o0 = c0[reg] + bias0;
            float o1 = c1[reg] + bias1;
            o0 = (o0 > 0.f) ? o0 : (__expf(o0) - 1.f);
            o1 = (o1 > 0.f) ? o1 : (__expf(o1) - 1.f);
            u.H[rr * HSTRIDE + h * 32 + col]      = f2bf(o0);
            u.H[rr * HSTRIDE + h * 32 + 16 + col] = f2bf(o1);
        }
    }
    __syncthreads();

    // ---- phase 2b: gemm2 — wave w covers col-tiles 2w, 2w+1 ----
    floatx4 acc[2];
    acc[0] = (floatx4){0.f, 0.f, 0.f, 0.f};
    acc[1] = (floatx4){0.f, 0.f, 0.f, 0.f};
    const bf16x8* pb = (const bf16x8*)W2p;
#pragma unroll
    for (int kb = 0; kb < 10; kb++) {
        bf16x8 a = *(const bf16x8*)&u.H[col * HSTRIDE + kb * 32 + quad * 8];
#pragma unroll
        for (int c = 0; c < 2; c++) {
            bf16x8 b = pb[(kb * 8 + (2 * wslot + c)) * 64 + lane];
            acc[c] = __builtin_amdgcn_mfma_f32_16x16x32_bf16(a, b, acc[c], 0, 0, 0);
        }
    }
    float asv[2], adv[2];
#pragma unroll
    for (int c = 0; c < 2; c++) {
        asv[c] = a_src[(2 * wslot + c) * 16 + col];
        adv[c] = a_dst[(2 * wslot + c) * 16 + col];
    }
#pragma unroll
    for (int reg = 0; reg < 4; reg++) {
        int row = row0 + quad * 4 + reg;
        float vs = 0.f, vd = 0.f;
#pragma unroll
        for (int c = 0; c < 2; c++) {
            float v = acc[c][reg];
            xw2h[(size_t)row * C2 + (2 * wslot + c) * 16 + col] = (f16)v;
            vs += v * asv[c];
            vd += v * adv[c];
        }
#pragma unroll
        for (int off = 8; off >= 1; off >>= 1) {
            vs += __shfl_xor(vs, off);
            vd += __shfl_xor(vd, off);
        }
        if (col == 0) { redS[wslot][quad * 4 + reg] = vs; redD[wslot][quad * 4 + reg] = vd; }
    }
    __syncthreads();
    if (wslot == 0) {
        if (lane < 16)
            s_src2[row0 + lane] = redS[0][lane] + redS[1][lane] + redS[2][lane] + redS[3][lane];
        else if (lane < 32) {
            int r2 = lane - 16;
            s_dst2[row0 + r2] = redD[0][r2] + redD[1][r2] + redD[2][r2] + redD[3][r2];
        }
    }
}

// ---------------------------------------------------------------------------
// Fused layer-2 aggregation + fc + distributed pooled-fc.
// Round-2 changes:
//  (a) TWO-SWEEP source-partitioned gather: xw2h is 5.12MB > 4MB per-XCD L2,
//      so random row reads thrashed to L3/HBM (~87MB stream). Ballot-compact
//      edges by src<SPLIT / src>=SPLIT; each sweep's working set (2.56MB)
//      is L2-resident. p computed once; denominator unchanged (sum reorder).
//  (b) pooled fc fused via per-graph completion counters: each graph = exactly
//      13 tiles; the tile whose atomicAdd(done[g]) returns 12 runs that
//      graph's fc. Winners spread over ~100 distinct blocks (NOT the round-14
//      single-CU serialization) and overlap the kernel tail.
// ---------------------------------------------------------------------------
__global__ __launch_bounds__(256) void agg2fc_kernel(
        const f16* __restrict__ xw2h, const float* __restrict__ s_src2,
        const float* __restrict__ s_dst2, const int* __restrict__ deg_arr,
        const int* __restrict__ csr_src, const float* __restrict__ b2,
        const f16* __restrict__ FCp, const float* __restrict__ fcb,
        const float* __restrict__ fcw,
        float* __restrict__ out, float* __restrict__ outp,
        int* __restrict__ pooledi, int* __restrict__ done) {
    __shared__ __align__(8) int2 shE[4][64];          // 2 KB
    __shared__ __align__(16) f16 X[16 * X2STRIDE];    // 4.25 KB
    __shared__ float pool_mx[C2];
    __shared__ float pool_part[2 * C2];
    __shared__ int win_s[2];
    int wslot = threadIdx.x >> 6;
    int lane = threadIdx.x & 63;
    int row0 = blockIdx.x * 16;          // 1250 blocks
    int2* E = shE[wslot];
    const char* xb = (const char*)xw2h + 4 * lane;    // lane's f16x2 column base

    // ---- phase 1: 4 nodes per wave, two-sweep gather ----
#pragma unroll
    for (int rep = 0; rep < 4; rep++) {
        int r = wslot * 4 + rep;
        int n = row0 + r;
        int beg = n * CAP, deg = deg_arr[n];
        float sd = s_dst2[n];
        float l = 0.f, a0 = 0.f, a1 = 0.f;

        for (int c0 = 0; c0 < deg; c0 += 64) {
            int dc = min(deg - c0, 64);
            bool act = lane < dc;
            int s_e = csr_src[beg + c0 + min(lane, dc - 1)];
            float e = s_src2[s_e] + sd;
            e = (e >= 0.f) ? e : 0.2f * e;
            float p = act ? __expf(e) : 0.f;
            float su = p;
#pragma unroll
            for (int off = 32; off >= 1; off >>= 1) su += __shfl_xor(su, off);
            l += su;

#pragma unroll
            for (int sw = 0; sw < 2; sw++) {
                bool sel = act && (sw ? (s_e >= SPLIT) : (s_e < SPLIT));
                unsigned long long m = __ballot(sel);
                int cnt = __popcll(m);
                int pos = __popcll(m & ((1ull << lane) - 1ull));
                if (sel) E[pos] = make_int2(s_e << 8, __float_as_int(p));
                int cntp = (cnt + 3) & ~3;
                if (lane >= cnt && lane < cntp) E[lane] = make_int2(0, 0);
                asm volatile("s_waitcnt lgkmcnt(0)" ::: "memory");

                for (int i = 0; i < cntp; i += 4) {
                    int2 e0 = E[i + 0], e1 = E[i + 1], e2 = E[i + 2], e3 = E[i + 3];
                    f16x2 v0 = *(const f16x2*)(xb + e0.x);
                    f16x2 v1 = *(const f16x2*)(xb + e1.x);
                    f16x2 v2 = *(const f16x2*)(xb + e2.x);
                    f16x2 v3 = *(const f16x2*)(xb + e3.x);
                    float p0 = __int_as_float(e0.y), p1 = __int_as_float(e1.y);
                    float p2 = __int_as_float(e2.y), p3 = __int_as_float(e3.y);
                    a0 += p0 * (float)v0.x + p1 * (float)v1.x + p2 * (float)v2.x + p3 * (float)v3.x;
                    a1 += p0 * (float)v0.y + p1 * (float)v1.y + p2 * (float)v2.y + p3 * (float)v3.y;
                }
                asm volatile("s_waitcnt lgkmcnt(0)" ::: "memory");   // E dead before next sweep
            }
        }

        float linv = 1.f / fmaxf(l, 1e-16f);
        float2 bb = *(const float2*)(b2 + 2 * lane);
        f16x2 o;
        o.x = (f16)fmaxf(a0 * linv + bb.x, 0.f);
        o.y = (f16)fmaxf(a1 * linv + bb.y, 0.f);
        *(f16x2*)&X[r * X2STRIDE + 2 * lane] = o;
    }
    __syncthreads();

    // ---- phase 2a: fc MFMA — wave w covers ct = 2w, 2w+1 ----
    int quad = lane >> 4, col = lane & 15;
    floatx4 acc[2];
    acc[0] = (floatx4){0.f, 0.f, 0.f, 0.f};
    acc[1] = (floatx4){0.f, 0.f, 0.f, 0.f};
    const f16x8* pb = (const f16x8*)FCp;
#pragma unroll
    for (int kb = 0; kb < 4; kb++) {
        f16x8 a = *(const f16x8*)&X[(lane & 15) * X2STRIDE + kb * 32 + quad * 8];
#pragma unroll
        for (int c = 0; c < 2; c++) {
            int ct = wslot * 2 + c;
            f16x8 b = pb[(kb * 8 + ct) * 64 + lane];
            acc[c] = __builtin_amdgcn_mfma_f32_16x16x32_f16(a, b, acc[c], 0, 0, 0);
        }
    }
#pragma unroll
    for (int c = 0; c < 2; c++) {
        int ct = wslot * 2 + c;
        float bias = fcb[ct * 16 + col];
#pragma unroll
        for (int reg = 0; reg < 4; reg++) {
            int row = row0 + quad * 4 + reg;
            out[(size_t)row * C2 + ct * 16 + col] = fmaxf(acc[c][reg] + bias, 0.f);
        }
    }

    // ---- phase 2b: tile-local pooling max + atomicMax (threads 0..127) ----
    int gA = row0 / PER;
    int gB = (row0 + 15) / PER;
    if (threadIdx.x < C2) {
        int c = threadIdx.x;
        float mA = 0.f, mB = 0.f;        // x2 >= 0, 0 is identity
#pragma unroll
        for (int r = 0; r < 16; r++) {
            float v = (float)X[r * X2STRIDE + c];
            if ((row0 + r) / PER == gA) mA = fmaxf(mA, v);
            else                        mB = fmaxf(mB, v);
        }
        atomicMax(&pooledi[gA * C2 + c], __float_as_int(mA));
        if (gB != gA) atomicMax(&pooledi[gB * C2 + c], __float_as_int(mB));
    }
    __syncthreads();   // barrier drains the atomics (vmcnt) for the whole block

    // ---- phase 2c: distributed pooled fc (winner = 13th tile of a graph) ----
    if (threadIdx.x == 0) {
        __threadfence();                               // publish our maxes
        int tA = atomicAdd(&done[gA], 1);
        int wA = (tA == 12);
        int wB = 0;
        if (gB != gA) { int tB = atomicAdd(&done[gB], 1); wB = (tB == 12); }
        win_s[0] = wA; win_s[1] = wB;
    }
    __syncthreads();

    auto pool_fc = [&](int g) {
        int t = threadIdx.x;
        if (t < C2)   // coherent read of the finished maxes
            pool_mx[t] = __int_as_float(atomicMax(&pooledi[g * C2 + t], 0));
        __syncthreads();
        int pc = t & (C2 - 1), piece = t >> 7;
        float acc2 = 0.f;
        const float* fw = fcw + (size_t)(piece * 64) * C2 + pc;
        const float* mp = pool_mx + piece * 64;
        for (int k = 0; k < 64; k++) acc2 += mp[k] * fw[(size_t)k * C2];
        pool_part[piece * C2 + pc] = acc2;
        __syncthreads();
        if (piece == 0)
            outp[(size_t)g * C2 + pc] = fmaxf(pool_part[pc] + pool_part[C2 + pc] + fcb[pc], 0.f);
    };
    if (win_s[0]) pool_fc(gA);
    if (win_s[1]) pool_fc(gB);
}

// ---------------------------------------------------------------------------
extern "C" void kernel_launch(void* const* d_in, const int* in_sizes, int n_in,
                              void* d_out, int out_size, void* d_ws, size_t ws_size,
                              hipStream_t stream) {
    const float* feats = (const float*)d_in[0];
    const int*   ei    = (const int*)d_in[1];
    const float* W1  = (const float*)d_in[4];
    const float* a1s = (const float*)d_in[5];
    const float* a1d = (const float*)d_in[6];
    const float* b1  = (const float*)d_in[7];
    const float* W2  = (const float*)d_in[8];
    const float* a2s = (const float*)d_in[9];
    const float* a2d = (const float*)d_in[10];
    const float* b2  = (const float*)d_in[11];
    const float* fcw = (const float*)d_in[12];
    const float* fcb = (const float*)d_in[13];

    float* out_main = (float*)d_out;                        // [20000,128]
    float* out_pool = (float*)d_out + (size_t)N_NODES * C2; // [100,128]

    char* p = (char*)d_ws;
    auto alloc = [&](size_t bytes) {
        char* r = p;
        p += (bytes + 255) & ~(size_t)255;
        return r;
    };
    unsigned short* W2p  = (unsigned short*)alloc(sizeof(short) * C1 * C2);
    unsigned short* W1p  = (unsigned short*)alloc(sizeof(short) * HEADS * F_IN * F_IN);
    f16*   FCp     = (f16*)alloc(sizeof(f16) * C2 * C2);
    f16*   feats16 = (f16*)alloc(sizeof(f16) * (size_t)N_NODES * F_IN);
    f16*   xw2h    = (f16*)alloc(sizeof(f16) * (size_t)N_NODES * C2);
    float* s1s    = (float*)alloc(sizeof(float) * N_NODES * HEADS);
    float* s1d    = (float*)alloc(sizeof(float) * N_NODES * HEADS);
    float* s2s    = (float*)alloc(sizeof(float) * N_NODES);
    float* s2d    = (float*)alloc(sizeof(float) * N_NODES);
    // zero region: cursor + pooledi + done in one memset
    const int NZ = N_NODES + NB * C2 + NB;
    int* zeros   = (int*)alloc(sizeof(int) * NZ);
    int* cursor  = zeros;
    int* pooledi = zeros + N_NODES;
    int* done    = zeros + N_NODES + NB * C2;
    int* csr_src = (int*)alloc(sizeof(int) * N_NODES * CAP); // bucket CSR

    hipMemsetAsync(zeros, 0, sizeof(int) * NZ, stream);

    mega_prep_kernel<<<SCAT_BLOCKS + SCORE_BLOCKS + W2P_BLOCKS + W1P_BLOCKS + FCP_BLOCKS + F16_BLOCKS,
                       256, 0, stream>>>(
        ei, cursor, csr_src, feats, feats16, W1, W1p, W2, W2p, fcw, FCp,
        a1s, a1d, s1s, s1d);

    agg1h1g2_kernel<<<1250, 256, 0, stream>>>(feats16, s1s, s1d, cursor, csr_src,
                                              W1p, b1, W2p, a2s, a2d, xw2h, s2s, s2d);
    agg2fc_kernel<<<1250, 256, 0, stream>>>(xw2h, s2s, s2d, cursor, csr_src, b2,
                                            FCp, fcb, fcw, out_main, out_pool,
                                            pooledi, done);
}

// Round 3
// 157.921 us; speedup vs baseline: 1.2824x; 1.2824x over previous
//
#include <hip/hip_runtime.h>

// Problem constants (fixed by the reference)
#define N_NODES 20000
#define N_EDGES 320000
#define ETOT    (N_EDGES + N_NODES)   // edges + self-loops = 340000
#define HEADS   10
#define F_IN    32
#define C1      (HEADS * F_IN)        // 320
#define C2      128
#define NB      100
#define PER     200
#define CAP     96                    // CSR bucket capacity (max in-degree << 96)
#define HSTRIDE 328                   // padded tile row stride (ushort); 328*2=656 is 16B-aligned
#define X2STRIDE 136                  // padded x2-tile row stride (f16); 136*2=272 is 16B-aligned

typedef __attribute__((ext_vector_type(8))) short bf16x8;   // MFMA A/B frag (4 VGPRs)
typedef __attribute__((ext_vector_type(4))) float floatx4;  // MFMA C/D frag
typedef _Float16 f16;
typedef _Float16 f16x2 __attribute__((ext_vector_type(2)));
typedef _Float16 f16x4 __attribute__((ext_vector_type(4)));
typedef _Float16 f16x8 __attribute__((ext_vector_type(8)));

static __device__ __forceinline__ unsigned short f2bf(float f) {
    unsigned int u = __float_as_uint(f);
    unsigned int r = (u + 0x7fffu + ((u >> 16) & 1u)) >> 16;   // RNE
    return (unsigned short)r;
}

// ---------------------------------------------------------------------------
// Mega prep: CSR scatter + layer-1 scores (local WA fold) + W2/W1/FC B-frag
// prep + feats->f16.  cursor/pooled zeroed by a prior hipMemsetAsync.
// All branches are independent work — no tail serialization.
// ---------------------------------------------------------------------------
#define SCAT_BLOCKS  ((ETOT + 255) / 256)               // 1329
#define SCORE_BLOCKS ((N_NODES + 63) / 64)              // 313
#define W2P_BLOCKS   ((C1 * C2 + 255) / 256)            // 160
#define W1P_BLOCKS   ((HEADS * F_IN * F_IN + 255) / 256)// 40
#define FCP_BLOCKS   ((C2 * C2 + 255) / 256)            // 64
#define F16_BLOCKS   ((N_NODES * F_IN / 4 + 255) / 256) // 625
__global__ __launch_bounds__(256) void mega_prep_kernel(
        const int* __restrict__ ei, int* __restrict__ cursor, int* __restrict__ csr_src,
        const float* __restrict__ feats, f16* __restrict__ feats16,
        const float* __restrict__ W1, unsigned short* __restrict__ W1p,
        const float* __restrict__ W2, unsigned short* __restrict__ W2p,
        const float* __restrict__ fcw, f16* __restrict__ FCp,
        const float* __restrict__ a1s, const float* __restrict__ a1d,
        float* __restrict__ s_src, float* __restrict__ s_dst) {
    unsigned int b = blockIdx.x;
    if (b < SCAT_BLOCKS) {
        int e = b * 256 + threadIdx.x;
        if (e >= ETOT) return;
        int s, d;
        if (e < N_EDGES) { s = ei[e]; d = ei[N_EDGES + e]; }
        else             { s = e - N_EDGES; d = s; }
        int pos = atomicAdd(&cursor[d], 1);
        csr_src[(size_t)d * CAP + pos] = s;
        return;
    }
    b -= SCAT_BLOCKS;
    if (b < SCORE_BLOCKS) {
        __shared__ __align__(16) float A[64 * F_IN];   // 8 KB
        __shared__ float Ws[C1], Wd[C1];
        int t = threadIdx.x;
        // fold attention vectors through W1 locally
        for (int o = t; o < C1; o += 256) {
            int k = o & 31, h = o >> 5;
            float ss = 0.f, dd = 0.f;
#pragma unroll
            for (int f = 0; f < F_IN; f++) {
                float wv = W1[k * C1 + h * 32 + f];
                ss += wv * a1s[h * 32 + f];
                dd += wv * a1d[h * 32 + f];
            }
            Ws[k * HEADS + h] = ss;
            Wd[k * HEADS + h] = dd;
        }
        int n0 = b * 64;
        int nrows = min(64, N_NODES - n0);
        const float4* fs = (const float4*)(feats + (size_t)n0 * F_IN);
        float4* Af = (float4*)A;
        for (int i = t; i < nrows * 8; i += 256) Af[i] = fs[i];
        __syncthreads();
        for (int o = t; o < nrows * HEADS; o += 256) {
            int nl = o / HEADS, h = o - nl * HEADS;
            const float* ar = A + nl * F_IN;
            float ss = 0.f, dd = 0.f;
#pragma unroll
            for (int k = 0; k < F_IN; k++) {
                float av = ar[k];
                ss += av * Ws[k * HEADS + h];
                dd += av * Wd[k * HEADS + h];
            }
            s_src[(size_t)(n0 + nl) * HEADS + h] = ss;
            s_dst[(size_t)(n0 + nl) * HEADS + h] = dd;
        }
        return;
    }
    b -= SCORE_BLOCKS;
    if (b < W2P_BLOCKS) {
        int o = b * 256 + threadIdx.x;   // 40960
        if (o >= C1 * C2) return;
        int j    = o & 7;
        int lane = (o >> 3) & 63;
        int ct   = (o >> 9) & 7;
        int kb   = o >> 12;
        int k = kb * 32 + (lane >> 4) * 8 + j;
        int n = ct * 16 + (lane & 15);
        W2p[o] = f2bf(W2[k * C2 + n]);
        return;
    }
    b -= W2P_BLOCKS;
    if (b < W1P_BLOCKS) {
        int o = b * 256 + threadIdx.x;   // 10240
        if (o >= HEADS * F_IN * F_IN) return;
        int j    = o & 7;
        int lane = (o >> 3) & 63;
        int ct   = (o >> 9) & 1;
        int h    = o >> 10;
        int k = (lane >> 4) * 8 + j;
        int f = ct * 16 + (lane & 15);
        W1p[o] = f2bf(W1[k * C1 + h * 32 + f]);
        return;
    }
    b -= W1P_BLOCKS;
    if (b < FCP_BLOCKS) {
        int o = b * 256 + threadIdx.x;   // 16384
        if (o >= C2 * C2) return;
        int j    = o & 7;
        int lane = (o >> 3) & 63;
        int ct   = (o >> 9) & 7;
        int kb   = o >> 12;
        int k = kb * 32 + (lane >> 4) * 8 + j;
        int n = ct * 16 + (lane & 15);
        FCp[o] = (f16)fcw[k * C2 + n];
        return;
    }
    b -= FCP_BLOCKS;
    {
        int o = b * 256 + threadIdx.x;
        if (o < N_NODES * F_IN / 4) {
            float4 v = ((const float4*)feats)[o];
            f16* d = feats16 + 4 * o;
            d[0] = (f16)v.x; d[1] = (f16)v.y; d[2] = (f16)v.z; d[3] = (f16)v.w;
        }
    }
}

// ---------------------------------------------------------------------------
// FUSED layer-1 aggregation + h1 transform + gemm2.  512 threads (round 3):
// phase 1 = ONE node per 32-lane half-wave (16 half-waves = 16 nodes, serial
// depth 1 vs round-1's 4). Paired halves run lockstep at max(trips) ~= 1
// chunk for Poisson(17) degrees. 4 blocks/CU resident = 32 waves/CU.
// Phase 2a: h1 = elu(G @ W1 + b1), heads strided over 8 waves.
// Phase 2b: gemm2 xw2 = H @ W2, 1 col-tile per wave + a2 scores.
// ---------------------------------------------------------------------------
__global__ __launch_bounds__(512) void agg1h1g2_kernel(
        const f16* __restrict__ feats16, const float* __restrict__ s_src,
        const float* __restrict__ s_dst, const int* __restrict__ deg_arr,
        const int* __restrict__ csr_src,
        const unsigned short* __restrict__ W1p, const float* __restrict__ b1,
        const unsigned short* __restrict__ W2p,
        const float* __restrict__ a_src, const float* __restrict__ a_dst,
        f16* __restrict__ xw2h, float* __restrict__ s_src2, float* __restrict__ s_dst2) {
    union Smem {
        struct { f16 P[16][HEADS * 32]; int S[16][32]; } p1;  // 10 KB + 2 KB
        unsigned short H[16 * HSTRIDE];                       // 10.25 KB
    };
    __shared__ __align__(16) Smem u;
    __shared__ __align__(16) unsigned short G[16 * HSTRIDE];  // gn tile, bf16
    __shared__ float redS[8][16], redD[8][16];

    int tid   = threadIdx.x;
    int wslot = tid >> 6;          // 0..7
    int lane  = tid & 63;
    int r     = tid >> 5;          // 0..15: node slot (one per half-wave)
    int l     = tid & 31;          // k-index and edge-slot
    int row0  = blockIdx.x * 16;   // 1250 blocks x 16 nodes
    f16* P = u.p1.P[r];
    int* S = u.p1.S[r];
    const f16x2 ones = {(f16)1.f, (f16)1.f};
    const char* fb = (const char*)feats16 + 2 * l;   // lane's k-column base

    // ---- phase 1: one node per half-wave ----
    {
        int n = row0 + r;
        int beg = n * CAP, deg = deg_arr[n];
        const float* sdp = s_dst + (size_t)n * HEADS;
        float sd[10];
#pragma unroll
        for (int q = 0; q < 5; q++) {
            float2 v = *(const float2*)(sdp + 2 * q);
            sd[2 * q] = v.x; sd[2 * q + 1] = v.y;
        }
        float g[10], la[10];
#pragma unroll
        for (int h = 0; h < 10; h++) { g[h] = 0.f; la[h] = 0.f; }

        for (int c0 = 0; c0 < deg; c0 += 32) {   // lockstep max over wave's 2 halves
            int dc = min(deg - c0, 32);
            bool act = l < dc;
            int s_e = csr_src[beg + c0 + min(l, dc - 1)];
            const float* ssp = s_src + (size_t)s_e * HEADS;
            float p[10];
#pragma unroll
            for (int q = 0; q < 5; q++) {
                float2 v = *(const float2*)(ssp + 2 * q);
                float e0 = v.x + sd[2 * q];
                float e1 = v.y + sd[2 * q + 1];
                e0 = (e0 >= 0.f) ? e0 : 0.2f * e0;   // leaky_relu(0.2)
                e1 = (e1 >= 0.f) ? e1 : 0.2f * e1;
                p[2 * q]     = act ? __expf(e0) : 0.f;
                p[2 * q + 1] = act ? __expf(e1) : 0.f;
            }
            S[l] = s_e << 6;   // BYTE offset: row = 32 f16 = 64 B
#pragma unroll
            for (int h = 0; h < 10; h++) P[h * 32 + l] = (f16)p[h];
            asm volatile("s_waitcnt lgkmcnt(0)" ::: "memory");

            int dcp = (dc + 1) & ~1;
            for (int i = 0; i < dcp; i += 2) {
                int2 ss2 = *(const int2*)&S[i];
                f16x2 v;
                v.x = *(const f16*)(fb + ss2.x);
                v.y = *(const f16*)(fb + ss2.y);
#pragma unroll
                for (int h = 0; h < 10; h++) {
                    f16x2 pp = *(const f16x2*)&P[h * 32 + i];
                    g[h]  = __builtin_amdgcn_fdot2(pp, v, g[h], false);
                    la[h] = __builtin_amdgcn_fdot2(pp, ones, la[h], false);
                }
            }
            asm volatile("s_waitcnt lgkmcnt(0)" ::: "memory");
        }
        unsigned short* gr = &G[r * HSTRIDE + l];
#pragma unroll
        for (int h = 0; h < 10; h++)
            gr[h * 32] = f2bf(g[h] / fmaxf(la[h], 1e-16f));
    }
    __syncthreads();   // G complete; P/S dead -> union region becomes H

    // ---- phase 2a: h1 = elu(G @ W1 + b1), heads strided over 8 waves ----
    int quad = lane >> 4, col = lane & 15;
    for (int h = wslot; h < 10; h += 8) {
        bf16x8 a = *(const bf16x8*)&G[col * HSTRIDE + h * 32 + quad * 8];
        bf16x8 bA = ((const bf16x8*)W1p)[(h * 2 + 0) * 64 + lane];
        bf16x8 bB = ((const bf16x8*)W1p)[(h * 2 + 1) * 64 + lane];
        floatx4 z = {0.f, 0.f, 0.f, 0.f};
        floatx4 c0 = __builtin_amdgcn_mfma_f32_16x16x32_bf16(a, bA, z, 0, 0, 0);
        floatx4 c1 = __builtin_amdgcn_mfma_f32_16x16x32_bf16(a, bB, z, 0, 0, 0);
        float bias0 = b1[h * 32 + col];
        float bias1 = b1[h * 32 + 16 + col];
#pragma unroll
        for (int reg = 0; reg < 4; reg++) {
            int rr = quad * 4 + reg;
            float o0 = c0[reg] + bias0;
            float o1 = c1[reg] + bias1;
            o0 = (o0 > 0.f) ? o0 : (__expf(o0) - 1.f);
            o1 = (o1 > 0.f) ? o1 : (__expf(o1) - 1.f);
            u.H[rr * HSTRIDE + h * 32 + col]      = f2bf(o0);
            u.H[rr * HSTRIDE + h * 32 + 16 + col] = f2bf(o1);
        }
    }
    __syncthreads();

    // ---- phase 2b: gemm2 — wave w covers col-tile w ----
    floatx4 acc = {0.f, 0.f, 0.f, 0.f};
    const bf16x8* pb = (const bf16x8*)W2p;
#pragma unroll
    for (int kb = 0; kb < 10; kb++) {
        bf16x8 a = *(const bf16x8*)&u.H[col * HSTRIDE + kb * 32 + quad * 8];
        bf16x8 b = pb[(kb * 8 + wslot) * 64 + lane];
        acc = __builtin_amdgcn_mfma_f32_16x16x32_bf16(a, b, acc, 0, 0, 0);
    }
    float asv = a_src[wslot * 16 + col];
    float adv = a_dst[wslot * 16 + col];
#pragma unroll
    for (int reg = 0; reg < 4; reg++) {
        int row = row0 + quad * 4 + reg;
        float v = acc[reg];
        xw2h[(size_t)row * C2 + wslot * 16 + col] = (f16)v;
        float vs = v * asv, vd = v * adv;
#pragma unroll
        for (int off = 8; off >= 1; off >>= 1) {
            vs += __shfl_xor(vs, off);
            vd += __shfl_xor(vd, off);
        }
        if (col == 0) { redS[wslot][quad * 4 + reg] = vs; redD[wslot][quad * 4 + reg] = vd; }
    }
    __syncthreads();
    if (wslot == 0) {
        if (lane < 16) {
            float s = 0.f;
#pragma unroll
            for (int w2 = 0; w2 < 8; w2++) s += redS[w2][lane];
            s_src2[row0 + lane] = s;
        } else if (lane < 32) {
            int r2 = lane - 16;
            float d = 0.f;
#pragma unroll
            for (int w2 = 0; w2 < 8; w2++) d += redD[w2][r2];
            s_dst2[row0 + r2] = d;
        }
    }
}

// ---------------------------------------------------------------------------
// Fused layer-2 aggregation + fc.  512 threads (round 3): one node per
// 32-lane half-wave (serial depth 1), 32 lanes x f16x4 covers the 256 B row.
// Single-sweep gather (round-2 two-sweep reverted: no phase separation in
// time -> no L2 benefit, pure ballot/barrier overhead on 17-edge chunks).
// Pooling via tile-local max + atomicMax; pooled fc is a SEPARATE kernel.
// ---------------------------------------------------------------------------
__global__ __launch_bounds__(512) void agg2fc_kernel(
        const f16* __restrict__ xw2h, const float* __restrict__ s_src2,
        const float* __restrict__ s_dst2, const int* __restrict__ deg_arr,
        const int* __restrict__ csr_src, const float* __restrict__ b2,
        const f16* __restrict__ FCp, const float* __restrict__ fcb,
        float* __restrict__ out, int* __restrict__ pooledi) {
    __shared__ __align__(8) int2 shE[16][32];         // 4 KB
    __shared__ __align__(16) f16 X[16 * X2STRIDE];    // 4.25 KB
    int tid   = threadIdx.x;
    int wslot = tid >> 6;
    int lane  = tid & 63;
    int r     = tid >> 5;          // 0..15: node slot
    int l     = tid & 31;
    int row0  = blockIdx.x * 16;   // 1250 blocks
    int2* E = shE[r];
    const char* xb = (const char*)xw2h + 8 * l;       // lane's f16x4 column base

    // ---- phase 1: one node per half-wave ----
    {
        int n = row0 + r;
        int beg = n * CAP, deg = deg_arr[n];
        float sd = s_dst2[n];
        float ldn = 0.f, a0 = 0.f, a1 = 0.f, a2 = 0.f, a3 = 0.f;

        for (int c0 = 0; c0 < deg; c0 += 32) {
            int dc = min(deg - c0, 32);
            bool act = l < dc;
            int s_e = csr_src[beg + c0 + min(l, dc - 1)];
            float e = s_src2[s_e] + sd;
            e = (e >= 0.f) ? e : 0.2f * e;
            float p = act ? __expf(e) : 0.f;
            float su = p;
#pragma unroll
            for (int off = 16; off >= 1; off >>= 1) su += __shfl_xor(su, off);
            ldn += su;

            E[l] = make_int2(s_e << 8, __float_as_int(p));  // BYTE offset: 128 f16 = 256 B
            asm volatile("s_waitcnt lgkmcnt(0)" ::: "memory");

            int dcr = (dc + 3) & ~3;                  // pad rows have p=0
            for (int i = 0; i < dcr; i += 4) {
                int2 e0 = E[i + 0], e1 = E[i + 1], e2 = E[i + 2], e3 = E[i + 3];
                f16x4 v0 = *(const f16x4*)(xb + e0.x);
                f16x4 v1 = *(const f16x4*)(xb + e1.x);
                f16x4 v2 = *(const f16x4*)(xb + e2.x);
                f16x4 v3 = *(const f16x4*)(xb + e3.x);
                float p0 = __int_as_float(e0.y), p1 = __int_as_float(e1.y);
                float p2 = __int_as_float(e2.y), p3 = __int_as_float(e3.y);
                a0 += p0 * (float)v0[0] + p1 * (float)v1[0] + p2 * (float)v2[0] + p3 * (float)v3[0];
                a1 += p0 * (float)v0[1] + p1 * (float)v1[1] + p2 * (float)v2[1] + p3 * (float)v3[1];
                a2 += p0 * (float)v0[2] + p1 * (float)v1[2] + p2 * (float)v2[2] + p3 * (float)v3[2];
                a3 += p0 * (float)v0[3] + p1 * (float)v1[3] + p2 * (float)v2[3] + p3 * (float)v3[3];
            }
            asm volatile("s_waitcnt lgkmcnt(0)" ::: "memory");
        }

        float linv = 1.f / fmaxf(ldn, 1e-16f);
        float4 bb = *(const float4*)(b2 + 4 * l);
        f16x4 o;
        o[0] = (f16)fmaxf(a0 * linv + bb.x, 0.f);
        o[1] = (f16)fmaxf(a1 * linv + bb.y, 0.f);
        o[2] = (f16)fmaxf(a2 * linv + bb.z, 0.f);
        o[3] = (f16)fmaxf(a3 * linv + bb.w, 0.f);
        *(f16x4*)&X[r * X2STRIDE + 4 * l] = o;
    }
    __syncthreads();

    // ---- phase 2a: fc MFMA — wave w covers col-tile w ----
    int quad = lane >> 4, col = lane & 15;
    floatx4 acc = {0.f, 0.f, 0.f, 0.f};
    const f16x8* pb = (const f16x8*)FCp;
#pragma unroll
    for (int kb = 0; kb < 4; kb++) {
        f16x8 a = *(const f16x8*)&X[col * X2STRIDE + kb * 32 + quad * 8];
        f16x8 b = pb[(kb * 8 + wslot) * 64 + lane];
        acc = __builtin_amdgcn_mfma_f32_16x16x32_f16(a, b, acc, 0, 0, 0);
    }
    float bias = fcb[wslot * 16 + col];
#pragma unroll
    for (int reg = 0; reg < 4; reg++) {
        int row = row0 + quad * 4 + reg;
        out[(size_t)row * C2 + wslot * 16 + col] = fmaxf(acc[reg] + bias, 0.f);
    }

    // ---- phase 2b: tile-local pooling max + atomicMax (threads 0..127) ----
    if (tid < C2) {
        int c = tid;
        int gA = row0 / PER;
        int gB = (row0 + 15) / PER;
        float mA = 0.f, mB = 0.f;        // x2 >= 0, 0 is identity
#pragma unroll
        for (int rr = 0; rr < 16; rr++) {
            float v = (float)X[rr * X2STRIDE + c];
            if ((row0 + rr) / PER == gA) mA = fmaxf(mA, v);
            else                         mB = fmaxf(mB, v);
        }
        atomicMax(&pooledi[gA * C2 + c], __float_as_int(mA));
        if (gB != gA) atomicMax(&pooledi[gB * C2 + c], __float_as_int(mB));
    }
}

// ---------------------------------------------------------------------------
// Final pooled fc: relu(pooled @ fc_w + fc_b)  — 100 parallel blocks
// ---------------------------------------------------------------------------
__global__ void poolfc_kernel(const int* __restrict__ pooledi, const float* __restrict__ fcw,
                              const float* __restrict__ fcb, float* __restrict__ outp) {
    __shared__ float mx[C2];
    int g = blockIdx.x, t = threadIdx.x;   // 128
    mx[t] = __int_as_float(pooledi[g * C2 + t]);
    __syncthreads();
    float acc = 0.f;
    for (int k = 0; k < C2; k++) acc += mx[k] * fcw[k * C2 + t];
    outp[g * C2 + t] = fmaxf(acc + fcb[t], 0.f);
}

// ---------------------------------------------------------------------------
extern "C" void kernel_launch(void* const* d_in, const int* in_sizes, int n_in,
                              void* d_out, int out_size, void* d_ws, size_t ws_size,
                              hipStream_t stream) {
    const float* feats = (const float*)d_in[0];
    const int*   ei    = (const int*)d_in[1];
    const float* W1  = (const float*)d_in[4];
    const float* a1s = (const float*)d_in[5];
    const float* a1d = (const float*)d_in[6];
    const float* b1  = (const float*)d_in[7];
    const float* W2  = (const float*)d_in[8];
    const float* a2s = (const float*)d_in[9];
    const float* a2d = (const float*)d_in[10];
    const float* b2  = (const float*)d_in[11];
    const float* fcw = (const float*)d_in[12];
    const float* fcb = (const float*)d_in[13];

    float* out_main = (float*)d_out;                        // [20000,128]
    float* out_pool = (float*)d_out + (size_t)N_NODES * C2; // [100,128]

    char* p = (char*)d_ws;
    auto alloc = [&](size_t bytes) {
        char* r = p;
        p += (bytes + 255) & ~(size_t)255;
        return r;
    };
    unsigned short* W2p  = (unsigned short*)alloc(sizeof(short) * C1 * C2);
    unsigned short* W1p  = (unsigned short*)alloc(sizeof(short) * HEADS * F_IN * F_IN);
    f16*   FCp     = (f16*)alloc(sizeof(f16) * C2 * C2);
    f16*   feats16 = (f16*)alloc(sizeof(f16) * (size_t)N_NODES * F_IN);
    f16*   xw2h    = (f16*)alloc(sizeof(f16) * (size_t)N_NODES * C2);
    float* s1s    = (float*)alloc(sizeof(float) * N_NODES * HEADS);
    float* s1d    = (float*)alloc(sizeof(float) * N_NODES * HEADS);
    float* s2s    = (float*)alloc(sizeof(float) * N_NODES);
    float* s2d    = (float*)alloc(sizeof(float) * N_NODES);
    // zero region: cursor + pooledi in one memset
    const int NZ = N_NODES + NB * C2;
    int* zeros   = (int*)alloc(sizeof(int) * NZ);
    int* cursor  = zeros;
    int* pooledi = zeros + N_NODES;
    int* csr_src = (int*)alloc(sizeof(int) * N_NODES * CAP); // bucket CSR

    hipMemsetAsync(zeros, 0, sizeof(int) * NZ, stream);

    mega_prep_kernel<<<SCAT_BLOCKS + SCORE_BLOCKS + W2P_BLOCKS + W1P_BLOCKS + FCP_BLOCKS + F16_BLOCKS,
                       256, 0, stream>>>(
        ei, cursor, csr_src, feats, feats16, W1, W1p, W2, W2p, fcw, FCp,
        a1s, a1d, s1s, s1d);

    agg1h1g2_kernel<<<1250, 512, 0, stream>>>(feats16, s1s, s1d, cursor, csr_src,
                                              W1p, b1, W2p, a2s, a2d, xw2h, s2s, s2d);
    agg2fc_kernel<<<1250, 512, 0, stream>>>(xw2h, s2s, s2d, cursor, csr_src, b2,
                                            FCp, fcb, out_main, pooledi);
    poolfc_kernel<<<NB, C2, 0, stream>>>(pooledi, fcw, fcb, out_pool);
}